// Round 6
// baseline (197.917 us; speedup 1.0000x reference)
//
#include <hip/hip_runtime.h>

#define S_ROWS 524288
#define D_COLS 63
#define BLOCK 256
#define GRID (S_ROWS / BLOCK)   // 2048 blocks, one thread per row
#define NACC 30
#define POSW 0.2f

// gate flag bits
#define F_CUB  1u
#define F_CUB2 2u
#define F_AP   4u
#define F_REF  8u
#define F_TR   16u
#define F_SQ   32u

enum {
  A_CMD_LOSS = 0, A_CMDC, A_MAE1, A_MAE2, A_MAE4, A_MAE5,
  A_CE_AP, A_CUBC,
  A_REF_AX_CE, A_REF_CUB_CE, A_REF_AXC, A_REF_CUBC,
  A_TR_AX_CE, A_TR_CUB_CE, A_TR_AXC, A_TR_CUBC,
  A_SQ_CUB_CE, A_FACE_CE, A_SQ_CUBC, A_FACEC,
  A_BCE, A_NPOS, A_NNEG, A_POSC, A_NEGC,
  A_NA, A_NC, A_NREF, A_NTR, A_NSQ
};

__device__ __forceinline__ float logsig(float x) {
  float ax = fabsf(x);
  return fminf(x, 0.f) - __logf(1.f + __expf(-ax));
}

// One CE slice [A,B): online argmax(t), argmax(p), p@argmax(t); p stored in
// compile-time-indexed regs for the exp-sum (no runtime reg indexing -> no scratch).
// Also accumulates this slice's MAE contribution.
template<int A, int B>
__device__ __forceinline__ void ce_slice(const float* __restrict__ pr,
                                         const float* __restrict__ tr,
                                         const float* __restrict__ wr,
                                         float& mae, float& ce, bool& ok, int& targ) {
  float ps[B - A];
  float tmax = 0.f, pmax = 0.f, ptv = 0.f;
  int ti = A, pi = A;
  #pragma unroll
  for (int j = A; j < B; ++j) {
    float pv = pr[j], tv = tr[j], wv = wr[j];
    mae += wv * fabsf(pv - tv);
    ps[j - A] = pv;
    if (j == A) {
      tmax = tv; ti = A; ptv = pv; pmax = pv; pi = A;
    } else {
      if (tv > tmax) { tmax = tv; ti = j; ptv = pv; }
      if (pv > pmax) { pmax = pv; pi = j; }
    }
  }
  float s = 0.f;
  #pragma unroll
  for (int k = 0; k < B - A; ++k) s += __expf(ps[k] - pmax);
  ce = pmax + __logf(s) - ptv;
  ok = (pi == ti);
  targ = ti - A;
}

template<int A, int B>
__device__ __forceinline__ void mae_slice(const float* __restrict__ pr,
                                          const float* __restrict__ tr,
                                          const float* __restrict__ wr,
                                          float& mae) {
  #pragma unroll
  for (int j = A; j < B; ++j) mae += wr[j] * fabsf(pr[j] - tr[j]);
}

__global__ void init_ws(float* ws) {
  int i = threadIdx.x;
  if (i < NACC) ws[i] = 0.f;
  unsigned* wu = (unsigned*)ws;
  if (i == NACC) wu[NACC] = 0xFFFFFFFFu;
  if (i == NACC + 1) wu[NACC + 1] = 0u;
}

__launch_bounds__(BLOCK, 4)
__global__ void prog_loss_main(const float* __restrict__ P,
                               const float* __restrict__ T,
                               const float* __restrict__ W,
                               float* __restrict__ ws) {
  __shared__ float sred[4][NACC];
  __shared__ unsigned sflags[4];
  __shared__ unsigned smin[4];

  const int tid = threadIdx.x;
  const int lane = tid & 63;
  const int wave = tid >> 6;

  const int row = blockIdx.x * BLOCK + tid;   // one thread per row, wave = 64 contiguous rows
  const size_t base = (size_t)row * D_COLS;
  const float* pr = P + base;
  const float* tr = T + base;
  const float* wr = W + base;

  // ---- single streaming pass over the row's 63 columns ----
  float mae = 0.f;
  float ceA, ceB, ceC, ceD, ceE, ceF;
  bool okA, okB, okC, okD, okE, okF;
  int c, dummy;

  ce_slice<0, 7>(pr, tr, wr, mae, ceA, okA, c);       // commands
  ce_slice<7, 18>(pr, tr, wr, mae, ceB, okB, dummy);  // cub 1
  ce_slice<18, 29>(pr, tr, wr, mae, ceC, okC, dummy); // cub 2
  ce_slice<29, 40>(pr, tr, wr, mae, ceD, okD, dummy); // cub 3
  mae_slice<40, 49>(pr, tr, wr, mae);
  ce_slice<49, 52>(pr, tr, wr, mae, ceE, okE, dummy); // axis
  mae_slice<52, 54>(pr, tr, wr, mae);
  ce_slice<54, 60>(pr, tr, wr, mae, ceF, okF, dummy); // face
  mae_slice<60, 62>(pr, tr, wr, mae);
  float p62 = pr[62], t62 = tr[62];
  mae += wr[62] * fabsf(p62 - t62);

  // ---- per-row accumulator assembly (compile-time indices only) ----
  float acc[NACC];
  #pragma unroll
  for (int v = 0; v < NACC; ++v) acc[v] = 0.f;
  unsigned fl = 0u;
  unsigned mymin = 0xFFFFFFFFu;
  const unsigned gr = (unsigned)row;

  acc[A_CMD_LOSS] = ceA;
  acc[A_CMDC] = okA ? 1.f : 0.f;

  if (c == 1) {
    acc[A_NC] = 1.f;
    acc[A_MAE1] = mae;
    float bce = -(POSW * t62 * logsig(p62) + (1.f - t62) * logsig(-p62));
    acc[A_BCE] = bce;
    bool pos = (t62 == 1.f), neg = (t62 == 0.f);
    acc[A_NPOS] = pos ? 1.f : 0.f;
    acc[A_NNEG] = neg ? 1.f : 0.f;
    acc[A_POSC] = (pos && p62 > 0.f) ? 1.f : 0.f;
    acc[A_NEGC] = (neg && p62 <= 0.f) ? 1.f : 0.f;
    if (gr >= 1u) fl |= F_CUB;
    if (gr >= 2u) fl |= F_CUB2;
    mymin = gr;
  } else if (c == 2) {
    acc[A_NA] = 1.f;
    acc[A_MAE2] = mae;
    acc[A_CE_AP] = ceB + ceC;
    acc[A_CUBC] = (okB && okC) ? 1.f : 0.f;
    if (gr >= 1u) fl |= F_AP;
  } else if (c == 3) {
    acc[A_NREF] = 1.f;
    acc[A_REF_CUB_CE] = ceB;
    acc[A_REF_CUBC] = okB ? 1.f : 0.f;
    acc[A_REF_AX_CE] = ceE;
    acc[A_REF_AXC] = okE ? 1.f : 0.f;
    if (gr >= 1u) fl |= F_REF;
  } else if (c == 4) {
    acc[A_NTR] = 1.f;
    acc[A_MAE4] = mae;
    acc[A_TR_CUB_CE] = ceB;
    acc[A_TR_CUBC] = okB ? 1.f : 0.f;
    acc[A_TR_AX_CE] = ceE;
    acc[A_TR_AXC] = okE ? 1.f : 0.f;
    if (gr >= 1u) fl |= F_TR;
  } else if (c == 5) {
    acc[A_NSQ] = 1.f;
    acc[A_MAE5] = mae;
    acc[A_SQ_CUB_CE] = ceB + ceC + ceD;
    acc[A_SQ_CUBC] = (okB && okC && okD) ? 1.f : 0.f;
    acc[A_FACE_CE] = ceF;
    acc[A_FACEC] = okF ? 1.f : 0.f;
    if (gr >= 1u) fl |= F_SQ;
  }

  // ---- reduction: wave shuffle -> LDS -> atomics ----
  #pragma unroll
  for (int v = 0; v < NACC; ++v) {
    float x = acc[v];
    #pragma unroll
    for (int off = 32; off > 0; off >>= 1) x += __shfl_down(x, off, 64);
    if (lane == 0) sred[wave][v] = x;
  }
  {
    unsigned f = fl, m = mymin;
    #pragma unroll
    for (int off = 32; off > 0; off >>= 1) {
      f |= __shfl_down(f, off, 64);
      unsigned om = __shfl_down(m, off, 64);
      m = (om < m) ? om : m;
    }
    if (lane == 0) { sflags[wave] = f; smin[wave] = m; }
  }
  __syncthreads();
  unsigned* wu = (unsigned*)ws;
  if (tid == 0) {
    unsigned f = sflags[0] | sflags[1] | sflags[2] | sflags[3];
    unsigned m = min(min(smin[0], smin[1]), min(smin[2], smin[3]));
    if (f) atomicOr(&wu[NACC + 1], f);
    if (m != 0xFFFFFFFFu) atomicMin(&wu[NACC], m);
  }
  if (tid < NACC) {
    float s = sred[0][tid] + sred[1][tid] + sred[2][tid] + sred[3][tid];
    if (s != 0.f) atomicAdd(&ws[tid], s);
  }
}

__global__ void finalize_k(const float* __restrict__ ws,
                           const float* __restrict__ P,
                           const float* __restrict__ T,
                           float* __restrict__ out) {
  const unsigned* wu = (const unsigned*)ws;
  unsigned flags = wu[NACC + 1];
  unsigned fm = wu[NACC];
  bool g_cub  = (flags & F_CUB)  != 0;
  bool g_cub2 = (flags & F_CUB2) != 0;
  bool g_ap   = (flags & F_AP)   != 0;
  bool g_ref  = (flags & F_REF)  != 0;
  bool g_tr   = (flags & F_TR)   != 0;
  bool g_sq   = (flags & F_SQ)   != 0;
  unsigned first = (fm == 0xFFFFFFFFu) ? 0u : fm;
  float x62 = P[(size_t)first * D_COLS + 62];
  float t62 = T[(size_t)first * D_COLS + 62];
  float bce_f = -(POSW * t62 * logsig(x62) + (1.f - t62) * logsig(-x62));
  float pos_f  = (t62 == 1.f) ? 1.f : 0.f;
  float neg_f  = (t62 == 0.f) ? 1.f : 0.f;
  float posc_f = (t62 == 1.f && x62 > 0.f) ? 1.f : 0.f;
  float negc_f = (t62 == 0.f && x62 <= 0.f) ? 1.f : 0.f;

  out[0]  = ws[A_CMD_LOSS];
  out[1]  = g_cub ? ws[A_MAE1] : 0.f;
  out[2]  = g_ap  ? ws[A_MAE2] : 0.f;
  out[3]  = g_sq  ? ws[A_MAE5] : 0.f;
  out[4]  = g_tr  ? ws[A_MAE4] : 0.f;
  out[5]  = g_ap  ? ws[A_CE_AP] : 0.f;
  out[6]  = g_sq  ? ws[A_SQ_CUB_CE] : 0.f;
  out[7]  = (g_ref ? ws[A_REF_CUB_CE] : 0.f) + (g_tr ? ws[A_TR_CUB_CE] : 0.f);
  out[8]  = (g_ref ? ws[A_REF_AX_CE]  : 0.f) + (g_tr ? ws[A_TR_AX_CE]  : 0.f);
  out[9]  = g_sq ? ws[A_FACE_CE] : 0.f;
  out[10] = ws[A_CMDC];
  out[11] = g_ap ? ws[A_CUBC] : 0.f;
  out[12] = g_sq ? ws[A_SQ_CUBC] : 0.f;
  out[13] = (g_ref ? ws[A_REF_CUBC] : 0.f) + (g_tr ? ws[A_TR_CUBC] : 0.f);
  out[14] = (g_ref ? ws[A_REF_AXC]  : 0.f) + (g_tr ? ws[A_TR_AXC]  : 0.f);
  out[15] = g_sq ? ws[A_FACEC] : 0.f;
  out[16] = g_cub2 ? (ws[A_BCE]  - bce_f)  : 0.f;
  out[17] = g_cub2 ? (ws[A_POSC] - posc_f) : 0.f;
  out[18] = g_cub2 ? (ws[A_NEGC] - negc_f) : 0.f;
  out[19] = g_cub2 ? (ws[A_NNEG] - neg_f)  : 0.f;
  out[20] = g_cub2 ? (ws[A_NPOS] - pos_f)  : 0.f;
  out[21] = ws[A_NA];
  out[22] = ws[A_NC];
  out[23] = ws[A_NREF] + ws[A_NTR];
  out[24] = ws[A_NSQ];
}

extern "C" void kernel_launch(void* const* d_in, const int* in_sizes, int n_in,
                              void* d_out, int out_size, void* d_ws, size_t ws_size,
                              hipStream_t stream) {
  const float* P = (const float*)d_in[0];
  const float* T = (const float*)d_in[1];
  const float* W = (const float*)d_in[2];
  float* ws = (float*)d_ws;
  float* out = (float*)d_out;

  hipLaunchKernelGGL(init_ws, dim3(1), dim3(64), 0, stream, ws);
  hipLaunchKernelGGL(prog_loss_main, dim3(GRID), dim3(BLOCK), 0, stream, P, T, W, ws);
  hipLaunchKernelGGL(finalize_k, dim3(1), dim3(1), 0, stream, ws, P, T, out);
}

// Round 7
// 123.193 us; speedup vs baseline: 1.6066x; 1.6066x over previous
//
#include <hip/hip_runtime.h>

#define S_ROWS 524288
#define D_COLS 63
#define TILE_ROWS 32
#define TILE_ELEMS (TILE_ROWS * D_COLS)   // 2016
#define TILE_VEC4 (TILE_ELEMS / 4)        // 504
#define BLOCK 128
#define GRID 1024
#define TILES_PER_BLOCK (S_ROWS / (TILE_ROWS * GRID))  // 16
#define NACC 30
#define POSW 0.2f

#define F_CUB  1u
#define F_CUB2 2u
#define F_AP   4u
#define F_REF  8u
#define F_TR   16u
#define F_SQ   32u

enum {
  A_CMD_LOSS = 0, A_CMDC, A_MAE1, A_MAE2, A_MAE4, A_MAE5,
  A_CE_AP, A_CUBC,
  A_REF_AX_CE, A_REF_CUB_CE, A_REF_AXC, A_REF_CUBC,
  A_TR_AX_CE, A_TR_CUB_CE, A_TR_AXC, A_TR_CUBC,
  A_SQ_CUB_CE, A_FACE_CE, A_SQ_CUBC, A_FACEC,
  A_BCE, A_NPOS, A_NNEG, A_POSC, A_NEGC,
  A_NA, A_NC, A_NREF, A_NTR, A_NSQ
};

#define GLOAD_LDS16(gptr, lptr) \
  __builtin_amdgcn_global_load_lds( \
      (const __attribute__((address_space(1))) void*)(gptr), \
      (__attribute__((address_space(3))) void*)(lptr), 16, 0, 0)

__device__ __forceinline__ float logsig(float x) {
  float ax = fabsf(x);
  return fminf(x, 0.f) - __logf(1.f + __expf(-ax));
}

__device__ __forceinline__ void slice_stats(const float* pr, const float* tr,
                                            int a, int b,
                                            int& targ, int& parg,
                                            float& lse, float& p_at_t) {
  float tmax = tr[a]; int ti = a;
  float pmax = pr[a]; int pi = a;
  #pragma unroll
  for (int j = a + 1; j < b; ++j) {
    float tv = tr[j]; if (tv > tmax) { tmax = tv; ti = j; }
    float pv = pr[j]; if (pv > pmax) { pmax = pv; pi = j; }
  }
  float se = 0.f;
  #pragma unroll
  for (int j = a; j < b; ++j) se += __expf(pr[j] - pmax);
  lse = pmax + __logf(se);
  targ = ti - a;
  parg = pi - a;
  p_at_t = pr[ti];
}

__global__ void init_ws(float* ws) {
  int i = threadIdx.x;
  if (i < NACC) ws[i] = 0.f;
  unsigned* wu = (unsigned*)ws;
  if (i == NACC) wu[NACC] = 0xFFFFFFFFu;
  if (i == NACC + 1) wu[NACC + 1] = 0u;
}

// stage one 32-row tile (P,T) into LDS via DMA: 8 wave-insts total per wave
__device__ __forceinline__ void stage_tile(const float* __restrict__ gP,
                                           const float* __restrict__ gT,
                                           float* lp, float* lt,
                                           int tid, int wave) {
  const float4* P4 = (const float4*)gP;
  const float4* T4 = (const float4*)gT;
  #pragma unroll
  for (int k = 0; k < 4; ++k) {
    int i = tid + k * BLOCK;
    int chunk = wave * 64 + k * BLOCK;  // wave-uniform f4 base; HW adds lane*16B
    if (i < TILE_VEC4) {
      GLOAD_LDS16(&P4[i], (float4*)lp + chunk);
      GLOAD_LDS16(&T4[i], (float4*)lt + chunk);
    }
  }
}

__launch_bounds__(BLOCK, 3)
__global__ void prog_loss_main(const float* __restrict__ P,
                               const float* __restrict__ T,
                               const float* __restrict__ W,
                               float* __restrict__ ws) {
  __shared__ float sp[2][TILE_ELEMS];
  __shared__ float st[2][TILE_ELEMS];
  __shared__ int scmd[TILE_ROWS];
  __shared__ int sokd[TILE_ROWS];
  __shared__ float sred[2][NACC];
  __shared__ unsigned sflags[2];
  __shared__ unsigned smin[2];

  const int tid = threadIdx.x;
  const int lane = tid & 63;
  const int wave = tid >> 6;      // 0,1
  const int half = (tid >> 5) & 1;
  const int r = tid & 31;         // row within tile for phase A

  float acc[NACC];
  #pragma unroll
  for (int v = 0; v < NACC; ++v) acc[v] = 0.f;
  unsigned fl = 0u;
  unsigned mymin = 0xFFFFFFFFu;

  const int tile0 = blockIdx.x * TILES_PER_BLOCK;

  // ---- prologue: DMA tile0 + W(tile0) -> 12 outstanding at loop entry ----
  stage_tile(P + (size_t)tile0 * TILE_ELEMS, T + (size_t)tile0 * TILE_ELEMS,
             sp[0], st[0], tid, wave);
  float4 wcur[4], wnext[4];
  {
    const float4* W4 = (const float4*)(W + (size_t)tile0 * TILE_ELEMS);
    #pragma unroll
    for (int k = 0; k < 4; ++k) {
      int i = tid + k * BLOCK;
      if (i < TILE_VEC4) wcur[k] = W4[i];
    }
  }
  asm volatile("" ::: "memory");

  #pragma unroll 1
  for (int tt = 0; tt < TILES_PER_BLOCK; ++tt) {
    const int tile = tile0 + tt;
    const int cur = tt & 1;

    // ---- issue next tile's DMA + next W; counted wait retires current 12 ----
    if (tt + 1 < TILES_PER_BLOCK) {
      const size_t nb = (size_t)(tile + 1) * TILE_ELEMS;
      stage_tile(P + nb, T + nb, sp[1 - cur], st[1 - cur], tid, wave);
      const float4* W4 = (const float4*)(W + nb);
      #pragma unroll
      for (int k = 0; k < 4; ++k) {
        int i = tid + k * BLOCK;
        if (i < TILE_VEC4) wnext[k] = W4[i];
      }
      asm volatile("" ::: "memory");
      asm volatile("s_waitcnt vmcnt(12)" ::: "memory");
    } else {
      asm volatile("s_waitcnt vmcnt(0)" ::: "memory");
    }
    __builtin_amdgcn_sched_barrier(0);
    __builtin_amdgcn_s_barrier();

    // ============ phase A: 4-way slice split {B | C | A+F | D+E+62}, lane=row ============
    const float* pr = sp[cur] + r * D_COLS;
    const float* tr = st[cur] + r * D_COLS;
    const unsigned gr = (unsigned)(tile * TILE_ROWS + r);

    // every phase-A thread computes its row's cmd (argmax T[0:7])
    int c;
    {
      float tm = tr[0]; c = 0;
      #pragma unroll
      for (int j = 1; j < 7; ++j) {
        float tv = tr[j]; if (tv > tm) { tm = tv; c = j; }
      }
    }

    int okB = 0;        // wave0-h0 keeps for joint counters
    int sendBC = 0;     // value shuffled within wave0 (h1 sends okC)
    int d0;

    if (wave == 0) {
      if (half == 0) {
        int c1, pc1; float lseB, pB; slice_stats(pr, tr, 7, 18, c1, pc1, lseB, pB);
        okB = (pc1 == c1) ? 1 : 0;
        float ceB = lseB - pB;
        if (c == 2)      acc[A_CE_AP] += ceB;
        else if (c == 3) { acc[A_REF_CUB_CE] += ceB; acc[A_REF_CUBC] += okB ? 1.f : 0.f; }
        else if (c == 4) { acc[A_TR_CUB_CE]  += ceB; acc[A_TR_CUBC]  += okB ? 1.f : 0.f; }
        else if (c == 5) acc[A_SQ_CUB_CE] += ceB;
        sendBC = okB;
      } else {
        int c2, pc2; float lseC, pC; slice_stats(pr, tr, 18, 29, c2, pc2, lseC, pC);
        int okC = (pc2 == c2) ? 1 : 0;
        float ceC = lseC - pC;
        if (c == 2)      acc[A_CE_AP] += ceC;
        else if (c == 5) acc[A_SQ_CUB_CE] += ceC;
        sendBC = okC;
      }
    } else {
      if (half == 0) {
        // A: cmd_loss/cmdc + scmd + counts + flags + min; F: face
        int ca, pca; float lseA, pA; slice_stats(pr, tr, 0, 7, ca, pca, lseA, pA);
        int fc, pfc; float lseF, pF; slice_stats(pr, tr, 54, 60, fc, pfc, lseF, pF);
        acc[A_CMD_LOSS] += lseA - pA;
        acc[A_CMDC] += (ca == pca) ? 1.f : 0.f;
        scmd[r] = c;
        if (c == 1) {
          acc[A_NC] += 1.f;
          if (gr >= 1u) fl |= F_CUB;
          if (gr >= 2u) fl |= F_CUB2;
          mymin = gr;
        } else if (c == 2) { acc[A_NA] += 1.f; if (gr >= 1u) fl |= F_AP; }
        else if (c == 3) { acc[A_NREF] += 1.f; if (gr >= 1u) fl |= F_REF; }
        else if (c == 4) { acc[A_NTR] += 1.f; if (gr >= 1u) fl |= F_TR; }
        else if (c == 5) {
          acc[A_NSQ] += 1.f;
          acc[A_FACE_CE] += lseF - pF;
          acc[A_FACEC] += (fc == pfc) ? 1.f : 0.f;
          if (gr >= 1u) fl |= F_SQ;
        }
      } else {
        // D + E + col62
        int c3, pc3; float lseD, pD; slice_stats(pr, tr, 29, 40, c3, pc3, lseD, pD);
        int ax, pax; float lseE, pE; slice_stats(pr, tr, 49, 52, ax, pax, lseE, pE);
        sokd[r] = (pc3 == c3) ? 1 : 0;
        float x62 = pr[62], t62 = tr[62];
        if (c == 1) {
          float bce = -(POSW * t62 * logsig(x62) + (1.f - t62) * logsig(-x62));
          acc[A_BCE] += bce;
          bool pos = (t62 == 1.f), neg = (t62 == 0.f);
          acc[A_NPOS] += pos ? 1.f : 0.f;
          acc[A_NNEG] += neg ? 1.f : 0.f;
          acc[A_POSC] += (pos && x62 > 0.f) ? 1.f : 0.f;
          acc[A_NEGC] += (neg && x62 <= 0.f) ? 1.f : 0.f;
        } else if (c == 3) {
          acc[A_REF_AX_CE] += lseE - pE;
          acc[A_REF_AXC] += (pax == ax) ? 1.f : 0.f;
        } else if (c == 4) {
          acc[A_TR_AX_CE] += lseE - pE;
          acc[A_TR_AXC] += (pax == ax) ? 1.f : 0.f;
        } else if (c == 5) {
          acc[A_SQ_CUB_CE] += lseD - pD;
        }
      }
    }
    // intra-wave: h0 lanes of wave0 receive okC from lane r+32
    int okCfrom = __shfl(sendBC, r + 32, 64);

    asm volatile("s_waitcnt lgkmcnt(0)" ::: "memory");  // scmd/sokd visible
    __builtin_amdgcn_s_barrier();

    // joint argmax counters (wave0-h0 only; needs sokd from wave1)
    if (wave == 0 && half == 0) {
      if (c == 2)      acc[A_CUBC]    += (okB && okCfrom) ? 1.f : 0.f;
      else if (c == 5) acc[A_SQ_CUBC] += (okB && okCfrom && sokd[r]) ? 1.f : 0.f;
    }

    // ============ phase B: masked MAE (all threads; W regs, P/T LDS) ============
    {
      const float4* sp4 = (const float4*)sp[cur];
      const float4* st4 = (const float4*)st[cur];
      #pragma unroll
      for (int k = 0; k < 4; ++k) {
        int i = tid + k * BLOCK;
        if (i < TILE_VEC4) {
          float4 w = wcur[k];
          float4 p = sp4[i];
          float4 t4v = st4[i];
          int e0 = i * 4;
          unsigned r0 = (unsigned)e0 / 63u;
          unsigned r3 = (unsigned)(e0 + 3) / 63u;
          int c0 = scmd[r0];
          int c3 = (r3 != r0) ? scmd[r3] : c0;
          float wv[4] = {w.x, w.y, w.z, w.w};
          float pv[4] = {p.x, p.y, p.z, p.w};
          float tv[4] = {t4v.x, t4v.y, t4v.z, t4v.w};
          #pragma unroll
          for (int q = 0; q < 4; ++q) {
            unsigned row = (unsigned)(e0 + q) / 63u;
            int cc = (row == r0) ? c0 : c3;
            float v = wv[q] * fabsf(pv[q] - tv[q]);
            acc[A_MAE1] += (cc == 1) ? v : 0.f;
            acc[A_MAE2] += (cc == 2) ? v : 0.f;
            acc[A_MAE4] += (cc == 4) ? v : 0.f;
            acc[A_MAE5] += (cc == 5) ? v : 0.f;
          }
        }
      }
    }
    // rotate W regs
    #pragma unroll
    for (int k = 0; k < 4; ++k) wcur[k] = wnext[k];

    asm volatile("s_waitcnt lgkmcnt(0)" ::: "memory");  // LDS reads retired
    __builtin_amdgcn_s_barrier();  // buffer about to be overwritten by next DMA
  }

  // ---- reduction: wave shuffle -> LDS -> atomics ----
  #pragma unroll
  for (int v = 0; v < NACC; ++v) {
    float x = acc[v];
    #pragma unroll
    for (int off = 32; off > 0; off >>= 1) x += __shfl_down(x, off, 64);
    if (lane == 0) sred[wave][v] = x;
  }
  {
    unsigned f = fl, m = mymin;
    #pragma unroll
    for (int off = 32; off > 0; off >>= 1) {
      f |= __shfl_down(f, off, 64);
      unsigned om = __shfl_down(m, off, 64);
      m = (om < m) ? om : m;
    }
    if (lane == 0) { sflags[wave] = f; smin[wave] = m; }
  }
  __syncthreads();
  unsigned* wu = (unsigned*)ws;
  if (tid == 0) {
    unsigned f = sflags[0] | sflags[1];
    unsigned m = min(smin[0], smin[1]);
    if (f) atomicOr(&wu[NACC + 1], f);
    if (m != 0xFFFFFFFFu) atomicMin(&wu[NACC], m);
  }
  if (tid < NACC) {
    float s = sred[0][tid] + sred[1][tid];
    if (s != 0.f) atomicAdd(&ws[tid], s);
  }
}

__global__ void finalize_k(const float* __restrict__ ws,
                           const float* __restrict__ P,
                           const float* __restrict__ T,
                           float* __restrict__ out) {
  const unsigned* wu = (const unsigned*)ws;
  unsigned flags = wu[NACC + 1];
  unsigned fm = wu[NACC];
  bool g_cub  = (flags & F_CUB)  != 0;
  bool g_cub2 = (flags & F_CUB2) != 0;
  bool g_ap   = (flags & F_AP)   != 0;
  bool g_ref  = (flags & F_REF)  != 0;
  bool g_tr   = (flags & F_TR)   != 0;
  bool g_sq   = (flags & F_SQ)   != 0;
  unsigned first = (fm == 0xFFFFFFFFu) ? 0u : fm;
  float x62 = P[(size_t)first * D_COLS + 62];
  float t62 = T[(size_t)first * D_COLS + 62];
  float bce_f = -(POSW * t62 * logsig(x62) + (1.f - t62) * logsig(-x62));
  float pos_f  = (t62 == 1.f) ? 1.f : 0.f;
  float neg_f  = (t62 == 0.f) ? 1.f : 0.f;
  float posc_f = (t62 == 1.f && x62 > 0.f) ? 1.f : 0.f;
  float negc_f = (t62 == 0.f && x62 <= 0.f) ? 1.f : 0.f;

  out[0]  = ws[A_CMD_LOSS];
  out[1]  = g_cub ? ws[A_MAE1] : 0.f;
  out[2]  = g_ap  ? ws[A_MAE2] : 0.f;
  out[3]  = g_sq  ? ws[A_MAE5] : 0.f;
  out[4]  = g_tr  ? ws[A_MAE4] : 0.f;
  out[5]  = g_ap  ? ws[A_CE_AP] : 0.f;
  out[6]  = g_sq  ? ws[A_SQ_CUB_CE] : 0.f;
  out[7]  = (g_ref ? ws[A_REF_CUB_CE] : 0.f) + (g_tr ? ws[A_TR_CUB_CE] : 0.f);
  out[8]  = (g_ref ? ws[A_REF_AX_CE]  : 0.f) + (g_tr ? ws[A_TR_AX_CE]  : 0.f);
  out[9]  = g_sq ? ws[A_FACE_CE] : 0.f;
  out[10] = ws[A_CMDC];
  out[11] = g_ap ? ws[A_CUBC] : 0.f;
  out[12] = g_sq ? ws[A_SQ_CUBC] : 0.f;
  out[13] = (g_ref ? ws[A_REF_CUBC] : 0.f) + (g_tr ? ws[A_TR_CUBC] : 0.f);
  out[14] = (g_ref ? ws[A_REF_AXC]  : 0.f) + (g_tr ? ws[A_TR_AXC]  : 0.f);
  out[15] = g_sq ? ws[A_FACEC] : 0.f;
  out[16] = g_cub2 ? (ws[A_BCE]  - bce_f)  : 0.f;
  out[17] = g_cub2 ? (ws[A_POSC] - posc_f) : 0.f;
  out[18] = g_cub2 ? (ws[A_NEGC] - negc_f) : 0.f;
  out[19] = g_cub2 ? (ws[A_NNEG] - neg_f)  : 0.f;
  out[20] = g_cub2 ? (ws[A_NPOS] - pos_f)  : 0.f;
  out[21] = ws[A_NA];
  out[22] = ws[A_NC];
  out[23] = ws[A_NREF] + ws[A_NTR];
  out[24] = ws[A_NSQ];
}

extern "C" void kernel_launch(void* const* d_in, const int* in_sizes, int n_in,
                              void* d_out, int out_size, void* d_ws, size_t ws_size,
                              hipStream_t stream) {
  const float* P = (const float*)d_in[0];
  const float* T = (const float*)d_in[1];
  const float* W = (const float*)d_in[2];
  float* ws = (float*)d_ws;
  float* out = (float*)d_out;

  hipLaunchKernelGGL(init_ws, dim3(1), dim3(64), 0, stream, ws);
  hipLaunchKernelGGL(prog_loss_main, dim3(GRID), dim3(BLOCK), 0, stream, P, T, W, ws);
  hipLaunchKernelGGL(finalize_k, dim3(1), dim3(1), 0, stream, ws, P, T, out);
}

// Round 8
// 116.834 us; speedup vs baseline: 1.6940x; 1.0544x over previous
//
#include <hip/hip_runtime.h>

#define S_ROWS 524288
#define D_COLS 63
#define TILE_ROWS 64
#define TILE_ELEMS (TILE_ROWS * D_COLS)   // 4032
#define TILE_VEC4 (TILE_ELEMS / 4)        // 1008
#define BLOCK 256
#define GRID 1024
#define TILES_PER_BLOCK (S_ROWS / (TILE_ROWS * GRID))  // 8
#define NACC 30
#define POSW 0.2f

#define F_CUB  1u
#define F_CUB2 2u
#define F_AP   4u
#define F_REF  8u
#define F_TR   16u
#define F_SQ   32u

enum {
  A_CMD_LOSS = 0, A_CMDC, A_MAE1, A_MAE2, A_MAE4, A_MAE5,
  A_CE_AP, A_CUBC,
  A_REF_AX_CE, A_REF_CUB_CE, A_REF_AXC, A_REF_CUBC,
  A_TR_AX_CE, A_TR_CUB_CE, A_TR_AXC, A_TR_CUBC,
  A_SQ_CUB_CE, A_FACE_CE, A_SQ_CUBC, A_FACEC,
  A_BCE, A_NPOS, A_NNEG, A_POSC, A_NEGC,
  A_NA, A_NC, A_NREF, A_NTR, A_NSQ
};

__device__ __forceinline__ float logsig(float x) {
  float ax = fabsf(x);
  return fminf(x, 0.f) - __logf(1.f + __expf(-ax));
}

__device__ __forceinline__ void slice_stats(const float* pr, const float* tr,
                                            int a, int b,
                                            int& targ, int& parg,
                                            float& lse, float& p_at_t) {
  float tmax = tr[a]; int ti = a;
  float pmax = pr[a]; int pi = a;
  #pragma unroll
  for (int j = a + 1; j < b; ++j) {
    float tv = tr[j]; if (tv > tmax) { tmax = tv; ti = j; }
    float pv = pr[j]; if (pv > pmax) { pmax = pv; pi = j; }
  }
  float se = 0.f;
  #pragma unroll
  for (int j = a; j < b; ++j) se += __expf(pr[j] - pmax);
  lse = pmax + __logf(se);
  targ = ti - a;
  parg = pi - a;
  p_at_t = pr[ti];
}

__global__ void init_ws(float* ws) {
  int i = threadIdx.x;
  if (i < NACC) ws[i] = 0.f;
  unsigned* wu = (unsigned*)ws;
  if (i == NACC) wu[NACC] = 0xFFFFFFFFu;
  if (i == NACC + 1) wu[NACC + 1] = 0u;
}

__device__ __forceinline__ void load_tile_regs(const float* __restrict__ g,
                                               float4* dst, int tid) {
  const float4* g4 = (const float4*)g;
  #pragma unroll
  for (int k = 0; k < 4; ++k) {
    int i = tid + k * BLOCK;
    if (i < TILE_VEC4) dst[k] = g4[i];
    else dst[k] = make_float4(0.f, 0.f, 0.f, 0.f);
  }
}

__launch_bounds__(BLOCK, 4)
__global__ void prog_loss_main(const float* __restrict__ P,
                               const float* __restrict__ T,
                               const float* __restrict__ W,
                               float* __restrict__ ws) {
  __shared__ float sp[TILE_ELEMS];
  __shared__ float st[TILE_ELEMS];
  __shared__ int scmd[TILE_ROWS];
  __shared__ float sred[4][NACC];
  __shared__ unsigned sflags[4];
  __shared__ unsigned smin[4];

  const int tid = threadIdx.x;
  const int lane = tid & 63;
  const int wave = tid >> 6;
  const int q = tid & 3;      // slice group within the row quad
  const int r = tid >> 2;     // row in tile 0..63

  float acc[NACC];
  #pragma unroll
  for (int v = 0; v < NACC; ++v) acc[v] = 0.f;
  unsigned fl = 0u;
  unsigned mymin = 0xFFFFFFFFu;

  const int tile0 = blockIdx.x * TILES_PER_BLOCK;

  float4 preg[4], treg[4], wreg[4];

  // ---- prologue: tile0 -> regs -> LDS ----
  load_tile_regs(P + (size_t)tile0 * TILE_ELEMS, preg, tid);
  load_tile_regs(T + (size_t)tile0 * TILE_ELEMS, treg, tid);
  asm volatile("s_waitcnt vmcnt(0)" ::: "memory");
  __builtin_amdgcn_sched_barrier(0);
  {
    float4* sp4 = (float4*)sp;
    float4* st4 = (float4*)st;
    #pragma unroll
    for (int k = 0; k < 4; ++k) {
      int i = tid + k * BLOCK;
      if (i < TILE_VEC4) { sp4[i] = preg[k]; st4[i] = treg[k]; }
    }
  }
  asm volatile("s_waitcnt lgkmcnt(0)" ::: "memory");
  __builtin_amdgcn_sched_barrier(0);
  __builtin_amdgcn_s_barrier();

  #pragma unroll 1
  for (int tt = 0; tt < TILES_PER_BLOCK; ++tt) {
    const int tile = tile0 + tt;
    const size_t base = (size_t)tile * TILE_ELEMS;

    // ---- issue W(t) then P,T(t+1): latency hides under phase A ----
    load_tile_regs(W + base, wreg, tid);
    if (tt + 1 < TILES_PER_BLOCK) {
      const size_t nb = base + TILE_ELEMS;
      load_tile_regs(P + nb, preg, tid);
      load_tile_regs(T + nb, treg, tid);
    }
    asm volatile("" ::: "memory");

    // ============ phase A: 4 lanes per row, slice-split {B|C|D|A+E+F+62} ============
    const float* pr = sp + r * D_COLS;
    const float* tr = st + r * D_COLS;
    const unsigned gr = (unsigned)(tile * TILE_ROWS + r);

    int c;        // row command
    int myok = 0; // this lane's slice argmax-match

    if (q == 3) {
      // slice A gives cmd directly, plus E, F, col62 work
      int ca, pca; float lseA, pA; slice_stats(pr, tr, 0, 7, ca, pca, lseA, pA);
      c = ca;
      int ax, pax; float lseE, pE; slice_stats(pr, tr, 49, 52, ax, pax, lseE, pE);
      int fc, pfc; float lseF, pF; slice_stats(pr, tr, 54, 60, fc, pfc, lseF, pF);
      acc[A_CMD_LOSS] += lseA - pA;
      acc[A_CMDC] += (ca == pca) ? 1.f : 0.f;
      scmd[r] = c;
      if (c == 1) {
        float x62 = pr[62], t62 = tr[62];
        acc[A_NC] += 1.f;
        float bce = -(POSW * t62 * logsig(x62) + (1.f - t62) * logsig(-x62));
        acc[A_BCE] += bce;
        bool pos = (t62 == 1.f), neg = (t62 == 0.f);
        acc[A_NPOS] += pos ? 1.f : 0.f;
        acc[A_NNEG] += neg ? 1.f : 0.f;
        acc[A_POSC] += (pos && x62 > 0.f) ? 1.f : 0.f;
        acc[A_NEGC] += (neg && x62 <= 0.f) ? 1.f : 0.f;
        if (gr >= 1u) fl |= F_CUB;
        if (gr >= 2u) fl |= F_CUB2;
        mymin = gr;
      } else if (c == 2) { acc[A_NA] += 1.f; if (gr >= 1u) fl |= F_AP; }
      else if (c == 3) {
        acc[A_NREF] += 1.f;
        acc[A_REF_AX_CE] += lseE - pE;
        acc[A_REF_AXC] += (pax == ax) ? 1.f : 0.f;
        if (gr >= 1u) fl |= F_REF;
      } else if (c == 4) {
        acc[A_NTR] += 1.f;
        acc[A_TR_AX_CE] += lseE - pE;
        acc[A_TR_AXC] += (pax == ax) ? 1.f : 0.f;
        if (gr >= 1u) fl |= F_TR;
      } else if (c == 5) {
        acc[A_NSQ] += 1.f;
        acc[A_FACE_CE] += lseF - pF;
        acc[A_FACEC] += (fc == pfc) ? 1.f : 0.f;
        if (gr >= 1u) fl |= F_SQ;
      }
    } else {
      // cmd = argmax T[0:7) (7 LDS reads)
      float tm = tr[0]; c = 0;
      #pragma unroll
      for (int j = 1; j < 7; ++j) {
        float tv = tr[j]; if (tv > tm) { tm = tv; c = j; }
      }
      if (q == 0) {
        int c1, pc1; float lseB, pB; slice_stats(pr, tr, 7, 18, c1, pc1, lseB, pB);
        myok = (pc1 == c1) ? 1 : 0;
        float ceB = lseB - pB;
        if (c == 2)      acc[A_CE_AP] += ceB;
        else if (c == 3) { acc[A_REF_CUB_CE] += ceB; acc[A_REF_CUBC] += myok ? 1.f : 0.f; }
        else if (c == 4) { acc[A_TR_CUB_CE]  += ceB; acc[A_TR_CUBC]  += myok ? 1.f : 0.f; }
        else if (c == 5) acc[A_SQ_CUB_CE] += ceB;
      } else if (q == 1) {
        int c2, pc2; float lseC, pC; slice_stats(pr, tr, 18, 29, c2, pc2, lseC, pC);
        myok = (pc2 == c2) ? 1 : 0;
        float ceC = lseC - pC;
        if (c == 2)      acc[A_CE_AP] += ceC;
        else if (c == 5) acc[A_SQ_CUB_CE] += ceC;
      } else {
        int c3, pc3; float lseD, pD; slice_stats(pr, tr, 29, 40, c3, pc3, lseD, pD);
        myok = (pc3 == c3) ? 1 : 0;
        if (c == 5) acc[A_SQ_CUB_CE] += lseD - pD;
      }
    }
    // joint argmax counters via intra-quad shuffles (convergent)
    {
      int b = lane & ~3;
      int okC = __shfl(myok, b + 1, 64);
      int okD = __shfl(myok, b + 2, 64);
      if (q == 0) {
        if (c == 2)      acc[A_CUBC]    += (myok && okC) ? 1.f : 0.f;
        else if (c == 5) acc[A_SQ_CUBC] += (myok && okC && okD) ? 1.f : 0.f;
      }
    }
    asm volatile("s_waitcnt lgkmcnt(0)" ::: "memory");  // scmd visible
    __builtin_amdgcn_sched_barrier(0);
    __builtin_amdgcn_s_barrier();

    // ---- W(t) must be in regs: counted wait retires the 4 oldest (W) only ----
    if (tt + 1 < TILES_PER_BLOCK) {
      asm volatile("s_waitcnt vmcnt(8)" ::: "memory");
    } else {
      asm volatile("s_waitcnt vmcnt(0)" ::: "memory");
    }
    __builtin_amdgcn_sched_barrier(0);

    // ============ phase B: masked MAE (all threads; W regs, P/T LDS) ============
    {
      const float4* sp4 = (const float4*)sp;
      const float4* st4 = (const float4*)st;
      #pragma unroll
      for (int k = 0; k < 4; ++k) {
        int i = tid + k * BLOCK;
        if (i < TILE_VEC4) {
          float4 w = wreg[k];
          float4 p = sp4[i];
          float4 t4v = st4[i];
          int e0 = i * 4;
          unsigned r0 = (unsigned)e0 / 63u;
          unsigned r3 = (unsigned)(e0 + 3) / 63u;
          int c0 = scmd[r0];
          int c3 = (r3 != r0) ? scmd[r3] : c0;
          float wv[4] = {w.x, w.y, w.z, w.w};
          float pv[4] = {p.x, p.y, p.z, p.w};
          float tv[4] = {t4v.x, t4v.y, t4v.z, t4v.w};
          #pragma unroll
          for (int qq = 0; qq < 4; ++qq) {
            unsigned row = (unsigned)(e0 + qq) / 63u;
            int cc = (row == r0) ? c0 : c3;
            float v = wv[qq] * fabsf(pv[qq] - tv[qq]);
            acc[A_MAE1] += (cc == 1) ? v : 0.f;
            acc[A_MAE2] += (cc == 2) ? v : 0.f;
            acc[A_MAE4] += (cc == 4) ? v : 0.f;
            acc[A_MAE5] += (cc == 5) ? v : 0.f;
          }
        }
      }
    }

    // ---- write NEXT tile from regs into the just-consumed slots (own slots only) ----
    if (tt + 1 < TILES_PER_BLOCK) {
      asm volatile("s_waitcnt vmcnt(0)" ::: "memory");
      __builtin_amdgcn_sched_barrier(0);
      float4* sp4 = (float4*)sp;
      float4* st4 = (float4*)st;
      #pragma unroll
      for (int k = 0; k < 4; ++k) {
        int i = tid + k * BLOCK;
        if (i < TILE_VEC4) { sp4[i] = preg[k]; st4[i] = treg[k]; }
      }
    }
    asm volatile("s_waitcnt lgkmcnt(0)" ::: "memory");  // writes + reads retired
    __builtin_amdgcn_sched_barrier(0);
    __builtin_amdgcn_s_barrier();
  }

  // ---- reduction: wave shuffle -> LDS -> atomics ----
  #pragma unroll
  for (int v = 0; v < NACC; ++v) {
    float x = acc[v];
    #pragma unroll
    for (int off = 32; off > 0; off >>= 1) x += __shfl_down(x, off, 64);
    if (lane == 0) sred[wave][v] = x;
  }
  {
    unsigned f = fl, m = mymin;
    #pragma unroll
    for (int off = 32; off > 0; off >>= 1) {
      f |= __shfl_down(f, off, 64);
      unsigned om = __shfl_down(m, off, 64);
      m = (om < m) ? om : m;
    }
    if (lane == 0) { sflags[wave] = f; smin[wave] = m; }
  }
  __syncthreads();
  unsigned* wu = (unsigned*)ws;
  if (tid == 0) {
    unsigned f = sflags[0] | sflags[1] | sflags[2] | sflags[3];
    unsigned m = min(min(smin[0], smin[1]), min(smin[2], smin[3]));
    if (f) atomicOr(&wu[NACC + 1], f);
    if (m != 0xFFFFFFFFu) atomicMin(&wu[NACC], m);
  }
  if (tid < NACC) {
    float s = sred[0][tid] + sred[1][tid] + sred[2][tid] + sred[3][tid];
    if (s != 0.f) atomicAdd(&ws[tid], s);
  }
}

__global__ void finalize_k(const float* __restrict__ ws,
                           const float* __restrict__ P,
                           const float* __restrict__ T,
                           float* __restrict__ out) {
  const unsigned* wu = (const unsigned*)ws;
  unsigned flags = wu[NACC + 1];
  unsigned fm = wu[NACC];
  bool g_cub  = (flags & F_CUB)  != 0;
  bool g_cub2 = (flags & F_CUB2) != 0;
  bool g_ap   = (flags & F_AP)   != 0;
  bool g_ref  = (flags & F_REF)  != 0;
  bool g_tr   = (flags & F_TR)   != 0;
  bool g_sq   = (flags & F_SQ)   != 0;
  unsigned first = (fm == 0xFFFFFFFFu) ? 0u : fm;
  float x62 = P[(size_t)first * D_COLS + 62];
  float t62 = T[(size_t)first * D_COLS + 62];
  float bce_f = -(POSW * t62 * logsig(x62) + (1.f - t62) * logsig(-x62));
  float pos_f  = (t62 == 1.f) ? 1.f : 0.f;
  float neg_f  = (t62 == 0.f) ? 1.f : 0.f;
  float posc_f = (t62 == 1.f && x62 > 0.f) ? 1.f : 0.f;
  float negc_f = (t62 == 0.f && x62 <= 0.f) ? 1.f : 0.f;

  out[0]  = ws[A_CMD_LOSS];
  out[1]  = g_cub ? ws[A_MAE1] : 0.f;
  out[2]  = g_ap  ? ws[A_MAE2] : 0.f;
  out[3]  = g_sq  ? ws[A_MAE5] : 0.f;
  out[4]  = g_tr  ? ws[A_MAE4] : 0.f;
  out[5]  = g_ap  ? ws[A_CE_AP] : 0.f;
  out[6]  = g_sq  ? ws[A_SQ_CUB_CE] : 0.f;
  out[7]  = (g_ref ? ws[A_REF_CUB_CE] : 0.f) + (g_tr ? ws[A_TR_CUB_CE] : 0.f);
  out[8]  = (g_ref ? ws[A_REF_AX_CE]  : 0.f) + (g_tr ? ws[A_TR_AX_CE]  : 0.f);
  out[9]  = g_sq ? ws[A_FACE_CE] : 0.f;
  out[10] = ws[A_CMDC];
  out[11] = g_ap ? ws[A_CUBC] : 0.f;
  out[12] = g_sq ? ws[A_SQ_CUBC] : 0.f;
  out[13] = (g_ref ? ws[A_REF_CUBC] : 0.f) + (g_tr ? ws[A_TR_CUBC] : 0.f);
  out[14] = (g_ref ? ws[A_REF_AXC]  : 0.f) + (g_tr ? ws[A_TR_AXC]  : 0.f);
  out[15] = g_sq ? ws[A_FACEC] : 0.f;
  out[16] = g_cub2 ? (ws[A_BCE]  - bce_f)  : 0.f;
  out[17] = g_cub2 ? (ws[A_POSC] - posc_f) : 0.f;
  out[18] = g_cub2 ? (ws[A_NEGC] - negc_f) : 0.f;
  out[19] = g_cub2 ? (ws[A_NNEG] - neg_f)  : 0.f;
  out[20] = g_cub2 ? (ws[A_NPOS] - pos_f)  : 0.f;
  out[21] = ws[A_NA];
  out[22] = ws[A_NC];
  out[23] = ws[A_NREF] + ws[A_NTR];
  out[24] = ws[A_NSQ];
}

extern "C" void kernel_launch(void* const* d_in, const int* in_sizes, int n_in,
                              void* d_out, int out_size, void* d_ws, size_t ws_size,
                              hipStream_t stream) {
  const float* P = (const float*)d_in[0];
  const float* T = (const float*)d_in[1];
  const float* W = (const float*)d_in[2];
  float* ws = (float*)d_ws;
  float* out = (float*)d_out;

  hipLaunchKernelGGL(init_ws, dim3(1), dim3(64), 0, stream, ws);
  hipLaunchKernelGGL(prog_loss_main, dim3(GRID), dim3(BLOCK), 0, stream, P, T, W, ws);
  hipLaunchKernelGGL(finalize_k, dim3(1), dim3(1), 0, stream, ws, P, T, out);
}

// Round 9
// 113.362 us; speedup vs baseline: 1.7459x; 1.0306x over previous
//
#include <hip/hip_runtime.h>

#define S_ROWS 524288
#define D_COLS 63
#define TILE_ROWS 64
#define TILE_ELEMS (TILE_ROWS * D_COLS)   // 4032
#define TILE_VEC4 (TILE_ELEMS / 4)        // 1008
#define BLOCK 256
#define GRID 1024
#define TILES_PER_BLOCK (S_ROWS / (TILE_ROWS * GRID))  // 8
#define NACC 30
#define POSW 0.2f

#define F_CUB  1u
#define F_CUB2 2u
#define F_AP   4u
#define F_REF  8u
#define F_TR   16u
#define F_SQ   32u

enum {
  A_CMD_LOSS = 0, A_CMDC, A_MAE1, A_MAE2, A_MAE4, A_MAE5,
  A_CE_AP, A_CUBC,
  A_REF_AX_CE, A_REF_CUB_CE, A_REF_AXC, A_REF_CUBC,
  A_TR_AX_CE, A_TR_CUB_CE, A_TR_AXC, A_TR_CUBC,
  A_SQ_CUB_CE, A_FACE_CE, A_SQ_CUBC, A_FACEC,
  A_BCE, A_NPOS, A_NNEG, A_POSC, A_NEGC,
  A_NA, A_NC, A_NREF, A_NTR, A_NSQ
};

__device__ __forceinline__ float logsig(float x) {
  float ax = fabsf(x);
  return fminf(x, 0.f) - __logf(1.f + __expf(-ax));
}

__device__ __forceinline__ void slice_stats(const float* pr, const float* tr,
                                            int a, int b,
                                            int& targ, int& parg,
                                            float& lse, float& p_at_t) {
  float tmax = tr[a]; int ti = a;
  float pmax = pr[a]; int pi = a;
  #pragma unroll
  for (int j = a + 1; j < b; ++j) {
    float tv = tr[j]; if (tv > tmax) { tmax = tv; ti = j; }
    float pv = pr[j]; if (pv > pmax) { pmax = pv; pi = j; }
  }
  float se = 0.f;
  #pragma unroll
  for (int j = a; j < b; ++j) se += __expf(pr[j] - pmax);
  lse = pmax + __logf(se);
  targ = ti - a;
  parg = pi - a;
  p_at_t = pr[ti];
}

__global__ void init_ws(float* ws) {
  int i = threadIdx.x;
  if (i < NACC) ws[i] = 0.f;
  unsigned* wu = (unsigned*)ws;
  if (i == NACC) wu[NACC] = 0xFFFFFFFFu;
  if (i == NACC + 1) wu[NACC + 1] = 0u;
}

__device__ __forceinline__ void load_tile_regs(const float* __restrict__ g,
                                               float4* dst, int tid) {
  const float4* g4 = (const float4*)g;
  #pragma unroll
  for (int k = 0; k < 4; ++k) {
    int i = tid + k * BLOCK;
    if (i < TILE_VEC4) dst[k] = g4[i];
    else dst[k] = make_float4(0.f, 0.f, 0.f, 0.f);
  }
}

__launch_bounds__(BLOCK, 4)
__global__ void prog_loss_main(const float* __restrict__ P,
                               const float* __restrict__ T,
                               const float* __restrict__ W,
                               float* __restrict__ ws) {
  __shared__ float sp[TILE_ELEMS];
  __shared__ float st[TILE_ELEMS];
  __shared__ int scmd[TILE_ROWS];
  __shared__ unsigned long long smaskC, smaskD;
  __shared__ float sred[4][NACC];
  __shared__ unsigned sflags[4];
  __shared__ unsigned smin[4];

  const int tid = threadIdx.x;
  const int lane = tid & 63;
  const int wave = tid >> 6;   // 0..3, slice group (wave-uniform!)
  const int r = lane;          // row in tile

  float acc[NACC];
  #pragma unroll
  for (int v = 0; v < NACC; ++v) acc[v] = 0.f;
  unsigned fl = 0u;
  unsigned mymin = 0xFFFFFFFFu;

  const int tile0 = blockIdx.x * TILES_PER_BLOCK;

  float4 preg[4], treg[4], wreg[4];

  // ---- prologue: tile0 -> regs -> LDS ----
  load_tile_regs(P + (size_t)tile0 * TILE_ELEMS, preg, tid);
  load_tile_regs(T + (size_t)tile0 * TILE_ELEMS, treg, tid);
  asm volatile("s_waitcnt vmcnt(0)" ::: "memory");
  __builtin_amdgcn_sched_barrier(0);
  {
    float4* sp4 = (float4*)sp;
    float4* st4 = (float4*)st;
    #pragma unroll
    for (int k = 0; k < 4; ++k) {
      int i = tid + k * BLOCK;
      if (i < TILE_VEC4) { sp4[i] = preg[k]; st4[i] = treg[k]; }
    }
  }
  asm volatile("s_waitcnt lgkmcnt(0)" ::: "memory");
  __builtin_amdgcn_sched_barrier(0);
  __builtin_amdgcn_s_barrier();

  #pragma unroll 1
  for (int tt = 0; tt < TILES_PER_BLOCK; ++tt) {
    const int tile = tile0 + tt;
    const size_t base = (size_t)tile * TILE_ELEMS;

    // ---- issue W(t) then P,T(t+1): latency hides under phase A ----
    load_tile_regs(W + base, wreg, tid);
    if (tt + 1 < TILES_PER_BLOCK) {
      const size_t nb = base + TILE_ELEMS;
      load_tile_regs(P + nb, preg, tid);
      load_tile_regs(T + nb, treg, tid);
    }
    asm volatile("" ::: "memory");

    // ============ phase A: wave-uniform slice split {B | C | D | A+E+F+62} ============
    const float* pr = sp + r * D_COLS;
    const float* tr = st + r * D_COLS;
    const unsigned gr = (unsigned)(tile * TILE_ROWS + r);

    int c;          // this row's command
    int okB = 0;    // wave0 keeps locally

    if (wave != 3) {
      // cmd = argmax T[0:7) (7 LDS reads, wave-uniform path)
      float tm = tr[0]; c = 0;
      #pragma unroll
      for (int j = 1; j < 7; ++j) {
        float tv = tr[j]; if (tv > tm) { tm = tv; c = j; }
      }
      if (wave == 0) {
        int c1, pc1; float lseB, pB; slice_stats(pr, tr, 7, 18, c1, pc1, lseB, pB);
        okB = (pc1 == c1) ? 1 : 0;
        float ceB = lseB - pB;
        if (c == 2)      acc[A_CE_AP] += ceB;
        else if (c == 3) { acc[A_REF_CUB_CE] += ceB; acc[A_REF_CUBC] += okB ? 1.f : 0.f; }
        else if (c == 4) { acc[A_TR_CUB_CE]  += ceB; acc[A_TR_CUBC]  += okB ? 1.f : 0.f; }
        else if (c == 5) acc[A_SQ_CUB_CE] += ceB;
      } else if (wave == 1) {
        int c2, pc2; float lseC, pC; slice_stats(pr, tr, 18, 29, c2, pc2, lseC, pC);
        int okC = (pc2 == c2) ? 1 : 0;
        float ceC = lseC - pC;
        if (c == 2)      acc[A_CE_AP] += ceC;
        else if (c == 5) acc[A_SQ_CUB_CE] += ceC;
        unsigned long long m = __ballot(okC != 0);
        if (lane == 0) smaskC = m;
      } else {
        int c3, pc3; float lseD, pD; slice_stats(pr, tr, 29, 40, c3, pc3, lseD, pD);
        int okD = (pc3 == c3) ? 1 : 0;
        if (c == 5) acc[A_SQ_CUB_CE] += lseD - pD;
        unsigned long long m = __ballot(okD != 0);
        if (lane == 0) smaskD = m;
      }
    } else {
      // wave 3: slice A (cmd_loss/cmdc/scmd), E, F, col62, counts, flags, min
      int ca, pca; float lseA, pA; slice_stats(pr, tr, 0, 7, ca, pca, lseA, pA);
      c = ca;
      int ax, pax; float lseE, pE; slice_stats(pr, tr, 49, 52, ax, pax, lseE, pE);
      int fc, pfc; float lseF, pF; slice_stats(pr, tr, 54, 60, fc, pfc, lseF, pF);
      acc[A_CMD_LOSS] += lseA - pA;
      acc[A_CMDC] += (ca == pca) ? 1.f : 0.f;
      scmd[r] = c;
      if (c == 1) {
        float x62 = pr[62], t62 = tr[62];
        acc[A_NC] += 1.f;
        float bce = -(POSW * t62 * logsig(x62) + (1.f - t62) * logsig(-x62));
        acc[A_BCE] += bce;
        bool pos = (t62 == 1.f), neg = (t62 == 0.f);
        acc[A_NPOS] += pos ? 1.f : 0.f;
        acc[A_NNEG] += neg ? 1.f : 0.f;
        acc[A_POSC] += (pos && x62 > 0.f) ? 1.f : 0.f;
        acc[A_NEGC] += (neg && x62 <= 0.f) ? 1.f : 0.f;
        if (gr >= 1u) fl |= F_CUB;
        if (gr >= 2u) fl |= F_CUB2;
        mymin = gr;
      } else if (c == 2) { acc[A_NA] += 1.f; if (gr >= 1u) fl |= F_AP; }
      else if (c == 3) {
        acc[A_NREF] += 1.f;
        acc[A_REF_AX_CE] += lseE - pE;
        acc[A_REF_AXC] += (pax == ax) ? 1.f : 0.f;
        if (gr >= 1u) fl |= F_REF;
      } else if (c == 4) {
        acc[A_NTR] += 1.f;
        acc[A_TR_AX_CE] += lseE - pE;
        acc[A_TR_AXC] += (pax == ax) ? 1.f : 0.f;
        if (gr >= 1u) fl |= F_TR;
      } else if (c == 5) {
        acc[A_NSQ] += 1.f;
        acc[A_FACE_CE] += lseF - pF;
        acc[A_FACEC] += (fc == pfc) ? 1.f : 0.f;
        if (gr >= 1u) fl |= F_SQ;
      }
    }
    asm volatile("s_waitcnt lgkmcnt(0)" ::: "memory");  // scmd + masks visible
    __builtin_amdgcn_sched_barrier(0);
    __builtin_amdgcn_s_barrier();

    // ---- wave0: joint argmax counters from the published bitmasks ----
    if (wave == 0) {
      unsigned long long mC = smaskC, mD = smaskD;
      int okC = (int)((mC >> r) & 1ull);
      int okD = (int)((mD >> r) & 1ull);
      if (c == 2)      acc[A_CUBC]    += (okB && okC) ? 1.f : 0.f;
      else if (c == 5) acc[A_SQ_CUBC] += (okB && okC && okD) ? 1.f : 0.f;
    }

    // ---- W(t) must be in regs: counted wait (8 P/T prefetch stay in flight) ----
    if (tt + 1 < TILES_PER_BLOCK) {
      asm volatile("s_waitcnt vmcnt(8)" ::: "memory");
    } else {
      asm volatile("s_waitcnt vmcnt(0)" ::: "memory");
    }
    __builtin_amdgcn_sched_barrier(0);

    // ============ phase B: masked MAE (all threads; W regs, P/T LDS) ============
    {
      const float4* sp4 = (const float4*)sp;
      const float4* st4 = (const float4*)st;
      #pragma unroll
      for (int k = 0; k < 4; ++k) {
        int i = tid + k * BLOCK;
        if (i < TILE_VEC4) {
          float4 w = wreg[k];
          float4 p = sp4[i];
          float4 t4v = st4[i];
          int e0 = i * 4;
          unsigned r0 = (unsigned)e0 / 63u;
          unsigned r3 = (unsigned)(e0 + 3) / 63u;
          int c0 = scmd[r0];
          int c3 = (r3 != r0) ? scmd[r3] : c0;
          float wv[4] = {w.x, w.y, w.z, w.w};
          float pv[4] = {p.x, p.y, p.z, p.w};
          float tv[4] = {t4v.x, t4v.y, t4v.z, t4v.w};
          #pragma unroll
          for (int qq = 0; qq < 4; ++qq) {
            unsigned row = (unsigned)(e0 + qq) / 63u;
            int cc = (row == r0) ? c0 : c3;
            float v = wv[qq] * fabsf(pv[qq] - tv[qq]);
            acc[A_MAE1] += (cc == 1) ? v : 0.f;
            acc[A_MAE2] += (cc == 2) ? v : 0.f;
            acc[A_MAE4] += (cc == 4) ? v : 0.f;
            acc[A_MAE5] += (cc == 5) ? v : 0.f;
          }
        }
      }
    }

    // ---- write NEXT tile from regs into the just-consumed slots (own slots only) ----
    if (tt + 1 < TILES_PER_BLOCK) {
      asm volatile("s_waitcnt vmcnt(0)" ::: "memory");
      __builtin_amdgcn_sched_barrier(0);
      float4* sp4 = (float4*)sp;
      float4* st4 = (float4*)st;
      #pragma unroll
      for (int k = 0; k < 4; ++k) {
        int i = tid + k * BLOCK;
        if (i < TILE_VEC4) { sp4[i] = preg[k]; st4[i] = treg[k]; }
      }
    }
    asm volatile("s_waitcnt lgkmcnt(0)" ::: "memory");  // writes + reads retired
    __builtin_amdgcn_sched_barrier(0);
    __builtin_amdgcn_s_barrier();
  }

  // ---- reduction: wave shuffle -> LDS -> atomics ----
  #pragma unroll
  for (int v = 0; v < NACC; ++v) {
    float x = acc[v];
    #pragma unroll
    for (int off = 32; off > 0; off >>= 1) x += __shfl_down(x, off, 64);
    if (lane == 0) sred[wave][v] = x;
  }
  {
    unsigned f = fl, m = mymin;
    #pragma unroll
    for (int off = 32; off > 0; off >>= 1) {
      f |= __shfl_down(f, off, 64);
      unsigned om = __shfl_down(m, off, 64);
      m = (om < m) ? om : m;
    }
    if (lane == 0) { sflags[wave] = f; smin[wave] = m; }
  }
  __syncthreads();
  unsigned* wu = (unsigned*)ws;
  if (tid == 0) {
    unsigned f = sflags[0] | sflags[1] | sflags[2] | sflags[3];
    unsigned m = min(min(smin[0], smin[1]), min(smin[2], smin[3]));
    if (f) atomicOr(&wu[NACC + 1], f);
    if (m != 0xFFFFFFFFu) atomicMin(&wu[NACC], m);
  }
  if (tid < NACC) {
    float s = sred[0][tid] + sred[1][tid] + sred[2][tid] + sred[3][tid];
    if (s != 0.f) atomicAdd(&ws[tid], s);
  }
}

__global__ void finalize_k(const float* __restrict__ ws,
                           const float* __restrict__ P,
                           const float* __restrict__ T,
                           float* __restrict__ out) {
  const unsigned* wu = (const unsigned*)ws;
  unsigned flags = wu[NACC + 1];
  unsigned fm = wu[NACC];
  bool g_cub  = (flags & F_CUB)  != 0;
  bool g_cub2 = (flags & F_CUB2) != 0;
  bool g_ap   = (flags & F_AP)   != 0;
  bool g_ref  = (flags & F_REF)  != 0;
  bool g_tr   = (flags & F_TR)   != 0;
  bool g_sq   = (flags & F_SQ)   != 0;
  unsigned first = (fm == 0xFFFFFFFFu) ? 0u : fm;
  float x62 = P[(size_t)first * D_COLS + 62];
  float t62 = T[(size_t)first * D_COLS + 62];
  float bce_f = -(POSW * t62 * logsig(x62) + (1.f - t62) * logsig(-x62));
  float pos_f  = (t62 == 1.f) ? 1.f : 0.f;
  float neg_f  = (t62 == 0.f) ? 1.f : 0.f;
  float posc_f = (t62 == 1.f && x62 > 0.f) ? 1.f : 0.f;
  float negc_f = (t62 == 0.f && x62 <= 0.f) ? 1.f : 0.f;

  out[0]  = ws[A_CMD_LOSS];
  out[1]  = g_cub ? ws[A_MAE1] : 0.f;
  out[2]  = g_ap  ? ws[A_MAE2] : 0.f;
  out[3]  = g_sq  ? ws[A_MAE5] : 0.f;
  out[4]  = g_tr  ? ws[A_MAE4] : 0.f;
  out[5]  = g_ap  ? ws[A_CE_AP] : 0.f;
  out[6]  = g_sq  ? ws[A_SQ_CUB_CE] : 0.f;
  out[7]  = (g_ref ? ws[A_REF_CUB_CE] : 0.f) + (g_tr ? ws[A_TR_CUB_CE] : 0.f);
  out[8]  = (g_ref ? ws[A_REF_AX_CE]  : 0.f) + (g_tr ? ws[A_TR_AX_CE]  : 0.f);
  out[9]  = g_sq ? ws[A_FACE_CE] : 0.f;
  out[10] = ws[A_CMDC];
  out[11] = g_ap ? ws[A_CUBC] : 0.f;
  out[12] = g_sq ? ws[A_SQ_CUBC] : 0.f;
  out[13] = (g_ref ? ws[A_REF_CUBC] : 0.f) + (g_tr ? ws[A_TR_CUBC] : 0.f);
  out[14] = (g_ref ? ws[A_REF_AXC]  : 0.f) + (g_tr ? ws[A_TR_AXC]  : 0.f);
  out[15] = g_sq ? ws[A_FACEC] : 0.f;
  out[16] = g_cub2 ? (ws[A_BCE]  - bce_f)  : 0.f;
  out[17] = g_cub2 ? (ws[A_POSC] - posc_f) : 0.f;
  out[18] = g_cub2 ? (ws[A_NEGC] - negc_f) : 0.f;
  out[19] = g_cub2 ? (ws[A_NNEG] - neg_f)  : 0.f;
  out[20] = g_cub2 ? (ws[A_NPOS] - pos_f)  : 0.f;
  out[21] = ws[A_NA];
  out[22] = ws[A_NC];
  out[23] = ws[A_NREF] + ws[A_NTR];
  out[24] = ws[A_NSQ];
}

extern "C" void kernel_launch(void* const* d_in, const int* in_sizes, int n_in,
                              void* d_out, int out_size, void* d_ws, size_t ws_size,
                              hipStream_t stream) {
  const float* P = (const float*)d_in[0];
  const float* T = (const float*)d_in[1];
  const float* W = (const float*)d_in[2];
  float* ws = (float*)d_ws;
  float* out = (float*)d_out;

  hipLaunchKernelGGL(init_ws, dim3(1), dim3(64), 0, stream, ws);
  hipLaunchKernelGGL(prog_loss_main, dim3(GRID), dim3(BLOCK), 0, stream, P, T, W, ws);
  hipLaunchKernelGGL(finalize_k, dim3(1), dim3(1), 0, stream, ws, P, T, out);
}